// Round 1
// baseline (767.035 us; speedup 1.0000x reference)
//
#include <hip/hip_runtime.h>

// RoIAlign (legacy, grid spacing roi/(P-1), PH=PW=8, zero for OOR samples)
// fused with 2x2 stride-1 max-pool -> out [R, C=256, 7, 7] float32.
//
// Shapes fixed by the problem: features [2, 256, 200, 272] f32, rois [R,5] f32.

#define FH 200
#define FW 272
#define FC 256
#define SPATIAL_SCALE 0.25f

__global__ __launch_bounds__(256) void roi_align_max_kernel(
    const float* __restrict__ feat,   // [B, C, H, W]
    const float* __restrict__ rois,   // [R, 5] (b, x1, y1, x2, y2)
    float* __restrict__ out,          // [R, C, 7, 7]
    int R)
{
    __shared__ int   s_off[64];    // y0*W + x0 per grid point
    __shared__ float s_w00[64], s_w01[64], s_w10[64], s_w11[64];
    __shared__ int   s_base;       // b * C*H*W

    const int r   = blockIdx.x;
    const int tid = threadIdx.x;

    if (tid < 64) {
        const float b  = rois[r * 5 + 0];
        const float x1 = rois[r * 5 + 1] * SPATIAL_SCALE;
        const float y1 = rois[r * 5 + 2] * SPATIAL_SCALE;
        const float x2 = rois[r * 5 + 3] * SPATIAL_SCALE;
        const float y2 = rois[r * 5 + 4] * SPATIAL_SCALE;
        const float bin_h = fmaxf(y2 - y1, 0.0f) * (1.0f / 7.0f);
        const float bin_w = fmaxf(x2 - x1, 0.0f) * (1.0f / 7.0f);

        const int ph = tid >> 3;
        const int pw = tid & 7;
        const float h = y1 + (float)ph * bin_h;
        const float w = x1 + (float)pw * bin_w;

        const bool valid = (h >= 0.0f) && (h < (float)FH) &&
                           (w >= 0.0f) && (w < (float)FW);
        // legacy: clip floor() into [0, H-2]; fractions NOT re-clamped
        const float h0 = fminf(fmaxf(floorf(h), 0.0f), (float)(FH - 2));
        const float w0 = fminf(fmaxf(floorf(w), 0.0f), (float)(FW - 2));
        const float fh = h - h0;
        const float fw = w - w0;
        const float v  = valid ? 1.0f : 0.0f;

        s_off[tid] = (int)h0 * FW + (int)w0;
        s_w00[tid] = (1.0f - fh) * (1.0f - fw) * v;
        s_w01[tid] = (1.0f - fh) * fw * v;
        s_w10[tid] = fh * (1.0f - fw) * v;
        s_w11[tid] = fh * fw * v;
        if (tid == 0) s_base = (int)b * (FC * FH * FW);
    }
    __syncthreads();

    const int c = tid;  // one thread per channel
    const float* __restrict__ f = feat + s_base + c * (FH * FW);
    float* __restrict__ outp = out + ((size_t)r * FC + c) * 49;

    float prev[8];
    for (int ph = 0; ph < 8; ++ph) {
        float cur[8];
        #pragma unroll
        for (int pw = 0; pw < 8; ++pw) {
            const int m = ph * 8 + pw;
            const int o = s_off[m];
            const float a00 = f[o];
            const float a01 = f[o + 1];
            const float a10 = f[o + FW];
            const float a11 = f[o + FW + 1];
            cur[pw] = a00 * s_w00[m] + a01 * s_w01[m]
                    + a10 * s_w10[m] + a11 * s_w11[m];
        }
        if (ph > 0) {
            #pragma unroll
            for (int ow = 0; ow < 7; ++ow) {
                const float m0 = fmaxf(prev[ow], prev[ow + 1]);
                const float m1 = fmaxf(cur[ow],  cur[ow + 1]);
                outp[(ph - 1) * 7 + ow] = fmaxf(m0, m1);
            }
        }
        #pragma unroll
        for (int pw = 0; pw < 8; ++pw) prev[pw] = cur[pw];
    }
}

extern "C" void kernel_launch(void* const* d_in, const int* in_sizes, int n_in,
                              void* d_out, int out_size, void* d_ws, size_t ws_size,
                              hipStream_t stream) {
    const float* feat = (const float*)d_in[0];
    const float* rois = (const float*)d_in[1];
    float* out = (float*)d_out;
    const int R = in_sizes[1] / 5;
    if (R <= 0) return;
    roi_align_max_kernel<<<R, 256, 0, stream>>>(feat, rois, out, R);
}

// Round 2
// 119.991 us; speedup vs baseline: 6.3924x; 6.3924x over previous
//
#include <hip/hip_runtime.h>

// RoIAlign (legacy, grid spacing roi/(P-1), PH=PW=8, zero for OOR samples)
// fused with 2x2 stride-1 max-pool -> out [R, C=256, 7, 7] float32.
//
// R2: transpose features to channels-last [B,H,W,C] in a pre-pass so the
// per-channel gather is coalesced (lane = channel, stride 4B), and stage the
// output tile in LDS for linear float4 stores.

#define FH 200
#define FW 272
#define FC 256
#define FHW (FH * FW)          // 54400
#define SPATIAL_SCALE 0.25f

// ---------------- transpose [B,C,HW] -> [B,HW,C] ----------------
__global__ __launch_bounds__(256) void transpose_kernel(
    const float* __restrict__ in, float* __restrict__ outT)
{
    __shared__ float tile[64][65];
    const int hw0  = blockIdx.x * 64;
    const int c0   = blockIdx.y * 64;
    const int b    = blockIdx.z;
    const int lane = threadIdx.x & 63;
    const int sub  = threadIdx.x >> 6;   // 0..3

    const float* inb = in + (size_t)b * FC * FHW;
    #pragma unroll
    for (int i = 0; i < 16; ++i) {
        const int c = sub * 16 + i;
        tile[c][lane] = inb[(size_t)(c0 + c) * FHW + hw0 + lane];
    }
    __syncthreads();
    float* outb = outT + (size_t)b * FHW * FC;
    #pragma unroll
    for (int i = 0; i < 16; ++i) {
        const int hw = sub * 16 + i;
        outb[(size_t)(hw0 + hw) * FC + c0 + lane] = tile[lane][hw];
    }
}

// ---------------- main: channels-last gather + fused pool ----------------
__global__ __launch_bounds__(256) void roi_align_max_t_kernel(
    const float* __restrict__ featT,  // [B, H, W, C]
    const float* __restrict__ rois,   // [R, 5]
    float* __restrict__ out,          // [R, C, 7, 7]
    int R)
{
    __shared__ int   s_off[64];    // ((y0*W + x0) * C) per grid point
    __shared__ float s_w00[64], s_w01[64], s_w10[64], s_w11[64];
    __shared__ int   s_base;       // b * H*W*C
    __shared__ float s_out[FC * 49];

    const int r   = blockIdx.x;
    const int tid = threadIdx.x;

    if (tid < 64) {
        const float b  = rois[r * 5 + 0];
        const float x1 = rois[r * 5 + 1] * SPATIAL_SCALE;
        const float y1 = rois[r * 5 + 2] * SPATIAL_SCALE;
        const float x2 = rois[r * 5 + 3] * SPATIAL_SCALE;
        const float y2 = rois[r * 5 + 4] * SPATIAL_SCALE;
        const float bin_h = fmaxf(y2 - y1, 0.0f) * (1.0f / 7.0f);
        const float bin_w = fmaxf(x2 - x1, 0.0f) * (1.0f / 7.0f);

        const int ph = tid >> 3;
        const int pw = tid & 7;
        const float h = y1 + (float)ph * bin_h;
        const float w = x1 + (float)pw * bin_w;

        const bool valid = (h >= 0.0f) && (h < (float)FH) &&
                           (w >= 0.0f) && (w < (float)FW);
        // legacy: clip floor() into [0, H-2]; fractions NOT re-clamped
        const float h0 = fminf(fmaxf(floorf(h), 0.0f), (float)(FH - 2));
        const float w0 = fminf(fmaxf(floorf(w), 0.0f), (float)(FW - 2));
        const float fh = h - h0;
        const float fw = w - w0;
        const float v  = valid ? 1.0f : 0.0f;

        s_off[tid] = ((int)h0 * FW + (int)w0) * FC;
        s_w00[tid] = (1.0f - fh) * (1.0f - fw) * v;
        s_w01[tid] = (1.0f - fh) * fw * v;
        s_w10[tid] = fh * (1.0f - fw) * v;
        s_w11[tid] = fh * fw * v;
        if (tid == 0) s_base = (int)b * (FHW * FC);
    }
    __syncthreads();

    const int c = tid;  // one thread per channel; lane stride = 4B
    const float* __restrict__ f = featT + s_base + c;

    float prev[8];
    for (int ph = 0; ph < 8; ++ph) {
        float cur[8];
        #pragma unroll
        for (int pw = 0; pw < 8; ++pw) {
            const int m = ph * 8 + pw;
            const int o = s_off[m];
            const float a00 = f[o];
            const float a01 = f[o + FC];
            const float a10 = f[o + FC * FW];
            const float a11 = f[o + FC * FW + FC];
            cur[pw] = a00 * s_w00[m] + a01 * s_w01[m]
                    + a10 * s_w10[m] + a11 * s_w11[m];
        }
        if (ph > 0) {
            #pragma unroll
            for (int ow = 0; ow < 7; ++ow) {
                const float m0 = fmaxf(prev[ow], prev[ow + 1]);
                const float m1 = fmaxf(cur[ow],  cur[ow + 1]);
                s_out[c * 49 + (ph - 1) * 7 + ow] = fmaxf(m0, m1);
            }
        }
        #pragma unroll
        for (int pw = 0; pw < 8; ++pw) prev[pw] = cur[pw];
    }
    __syncthreads();

    // coalesced float4 writeout of this roi's [C,7,7] slab
    const float4* s4 = (const float4*)s_out;
    float4* o4 = (float4*)(out + (size_t)r * (FC * 49));
    for (int idx = tid; idx < (FC * 49 / 4); idx += 256) o4[idx] = s4[idx];
}

// ---------------- fallback (R1 kernel, used only if ws too small) --------
__global__ __launch_bounds__(256) void roi_align_max_kernel(
    const float* __restrict__ feat, const float* __restrict__ rois,
    float* __restrict__ out, int R)
{
    __shared__ int   s_off[64];
    __shared__ float s_w00[64], s_w01[64], s_w10[64], s_w11[64];
    __shared__ int   s_base;

    const int r   = blockIdx.x;
    const int tid = threadIdx.x;

    if (tid < 64) {
        const float b  = rois[r * 5 + 0];
        const float x1 = rois[r * 5 + 1] * SPATIAL_SCALE;
        const float y1 = rois[r * 5 + 2] * SPATIAL_SCALE;
        const float x2 = rois[r * 5 + 3] * SPATIAL_SCALE;
        const float y2 = rois[r * 5 + 4] * SPATIAL_SCALE;
        const float bin_h = fmaxf(y2 - y1, 0.0f) * (1.0f / 7.0f);
        const float bin_w = fmaxf(x2 - x1, 0.0f) * (1.0f / 7.0f);
        const int ph = tid >> 3;
        const int pw = tid & 7;
        const float h = y1 + (float)ph * bin_h;
        const float w = x1 + (float)pw * bin_w;
        const bool valid = (h >= 0.0f) && (h < (float)FH) &&
                           (w >= 0.0f) && (w < (float)FW);
        const float h0 = fminf(fmaxf(floorf(h), 0.0f), (float)(FH - 2));
        const float w0 = fminf(fmaxf(floorf(w), 0.0f), (float)(FW - 2));
        const float fh = h - h0;
        const float fw = w - w0;
        const float v  = valid ? 1.0f : 0.0f;
        s_off[tid] = (int)h0 * FW + (int)w0;
        s_w00[tid] = (1.0f - fh) * (1.0f - fw) * v;
        s_w01[tid] = (1.0f - fh) * fw * v;
        s_w10[tid] = fh * (1.0f - fw) * v;
        s_w11[tid] = fh * fw * v;
        if (tid == 0) s_base = (int)b * (FC * FHW);
    }
    __syncthreads();

    const int c = tid;
    const float* __restrict__ f = feat + s_base + c * FHW;
    float* __restrict__ outp = out + ((size_t)r * FC + c) * 49;

    float prev[8];
    for (int ph = 0; ph < 8; ++ph) {
        float cur[8];
        #pragma unroll
        for (int pw = 0; pw < 8; ++pw) {
            const int m = ph * 8 + pw;
            const int o = s_off[m];
            cur[pw] = f[o] * s_w00[m] + f[o + 1] * s_w01[m]
                    + f[o + FW] * s_w10[m] + f[o + FW + 1] * s_w11[m];
        }
        if (ph > 0) {
            #pragma unroll
            for (int ow = 0; ow < 7; ++ow)
                outp[(ph - 1) * 7 + ow] =
                    fmaxf(fmaxf(prev[ow], prev[ow + 1]),
                          fmaxf(cur[ow],  cur[ow + 1]));
        }
        #pragma unroll
        for (int pw = 0; pw < 8; ++pw) prev[pw] = cur[pw];
    }
}

extern "C" void kernel_launch(void* const* d_in, const int* in_sizes, int n_in,
                              void* d_out, int out_size, void* d_ws, size_t ws_size,
                              hipStream_t stream) {
    const float* feat = (const float*)d_in[0];
    const float* rois = (const float*)d_in[1];
    float* out = (float*)d_out;
    const int R = in_sizes[1] / 5;
    if (R <= 0) return;

    const size_t needed = (size_t)2 * FC * FHW * sizeof(float);  // 111.4 MB
    if (ws_size >= needed) {
        float* featT = (float*)d_ws;
        transpose_kernel<<<dim3(FHW / 64, FC / 64, 2), 256, 0, stream>>>(feat, featT);
        roi_align_max_t_kernel<<<R, 256, 0, stream>>>(featT, rois, out, R);
    } else {
        roi_align_max_kernel<<<R, 256, 0, stream>>>(feat, rois, out, R);
    }
}

// Round 3
// 86.908 us; speedup vs baseline: 8.8258x; 1.3807x over previous
//
#include <hip/hip_runtime.h>
#include <hip/hip_fp16.h>

// RoIAlign (legacy, grid spacing roi/(P-1), PH=PW=8, zero for OOR samples)
// fused with 2x2 stride-1 max-pool -> out [R, C=256, 7, 7] float32.
//
// R3: features transposed+converted to channels-last f16 [B,H,W,C] (56 MB,
// L3-resident). Main kernel: thread = channel PAIR (__half2 loads, 4B/lane),
// 2 row-half groups, results in registers, output staged through a 25 KB LDS
// buffer in two 128-channel phases for dense float4 stores.

#define FH 200
#define FW 272
#define FC 256
#define FHW (FH * FW)          // 54400
#define SPATIAL_SCALE 0.25f

// ---------------- transpose+convert [B,C,HW] f32 -> [B,HW,C] f16 ----------
__global__ __launch_bounds__(256) void transpose_f16_kernel(
    const float* __restrict__ in, __half* __restrict__ outT)
{
    __shared__ float tile[64][65];
    const int hw0  = blockIdx.x * 64;
    const int c0   = blockIdx.y * 64;
    const int b    = blockIdx.z;
    const int lane = threadIdx.x & 63;
    const int sub  = threadIdx.x >> 6;   // 0..3

    const float* inb = in + (size_t)b * FC * FHW;
    #pragma unroll
    for (int i = 0; i < 16; ++i) {
        const int c = sub * 16 + i;
        tile[c][lane] = inb[(size_t)(c0 + c) * FHW + hw0 + lane];
    }
    __syncthreads();
    __half* outb = outT + (size_t)b * FHW * FC;
    #pragma unroll
    for (int i = 0; i < 16; ++i) {
        const int hw = sub * 16 + i;
        outb[(size_t)(hw0 + hw) * FC + c0 + lane] = __float2half(tile[lane][hw]);
    }
}

// ---------------- main: f16 channels-last gather + fused pool -------------
__global__ __launch_bounds__(256, 4) void roi_align_max_f16_kernel(
    const __half2* __restrict__ featT,  // [B, H, W, C/2] half2
    const float* __restrict__ rois,     // [R, 5]
    float* __restrict__ out,            // [R, C, 7, 7]
    int R)
{
    __shared__ int   s_off[64];          // (y0*W + x0) * (C/2), half2 units
    __shared__ float s_w0[64], s_w1[64], s_w2[64], s_w3[64];
    __shared__ int   s_base;             // b * H*W*(C/2)
    __shared__ float s_out[128 * 49];    // one 128-channel group (25 KB)

    const int r   = blockIdx.x;
    const int tid = threadIdx.x;

    if (tid < 64) {
        const float b  = rois[r * 5 + 0];
        const float x1 = rois[r * 5 + 1] * SPATIAL_SCALE;
        const float y1 = rois[r * 5 + 2] * SPATIAL_SCALE;
        const float x2 = rois[r * 5 + 3] * SPATIAL_SCALE;
        const float y2 = rois[r * 5 + 4] * SPATIAL_SCALE;
        const float bin_h = fmaxf(y2 - y1, 0.0f) * (1.0f / 7.0f);
        const float bin_w = fmaxf(x2 - x1, 0.0f) * (1.0f / 7.0f);

        const int ph = tid >> 3;
        const int pw = tid & 7;
        const float h = y1 + (float)ph * bin_h;
        const float w = x1 + (float)pw * bin_w;

        const bool valid = (h >= 0.0f) && (h < (float)FH) &&
                           (w >= 0.0f) && (w < (float)FW);
        // legacy: clip floor() into [0, H-2]; fractions NOT re-clamped
        const float h0 = fminf(fmaxf(floorf(h), 0.0f), (float)(FH - 2));
        const float w0 = fminf(fmaxf(floorf(w), 0.0f), (float)(FW - 2));
        const float fh = h - h0;
        const float fw = w - w0;
        const float v  = valid ? 1.0f : 0.0f;

        s_off[tid] = ((int)h0 * FW + (int)w0) * (FC / 2);
        s_w0[tid] = (1.0f - fh) * (1.0f - fw) * v;
        s_w1[tid] = (1.0f - fh) * fw * v;
        s_w2[tid] = fh * (1.0f - fw) * v;
        s_w3[tid] = fh * fw * v;
        if (tid == 0) s_base = (int)b * (FHW * (FC / 2));
    }
    __syncthreads();

    const int cp   = tid & 127;   // channel pair: channels 2cp, 2cp+1
    const int half = tid >> 7;    // 0: out rows 0..2 ; 1: out rows 3..6
    const __half2* __restrict__ f = featT + s_base + cp;

    // one bilinear-sampled aligned row (8 grid points, 2 channels)
    auto sample_row = [&](int ph, float2* cur) {
        #pragma unroll
        for (int pw = 0; pw < 8; ++pw) {
            const int m = ph * 8 + pw;
            const int o = s_off[m];
            const float2 a00 = __half22float2(f[o]);
            const float2 a01 = __half22float2(f[o + (FC / 2)]);
            const float2 a10 = __half22float2(f[o + FW * (FC / 2)]);
            const float2 a11 = __half22float2(f[o + FW * (FC / 2) + (FC / 2)]);
            const float w0v = s_w0[m], w1v = s_w1[m], w2v = s_w2[m], w3v = s_w3[m];
            cur[pw].x = a00.x * w0v + a01.x * w1v + a10.x * w2v + a11.x * w3v;
            cur[pw].y = a00.y * w0v + a01.y * w1v + a10.y * w2v + a11.y * w3v;
        }
    };

    float2 res[4][7];   // half0 uses rows [0..2]; half1 uses [0..3]
    if (half == 0) {
        float2 prev[8], cur[8];
        sample_row(0, prev);
        #pragma unroll
        for (int j = 0; j < 3; ++j) {
            sample_row(j + 1, cur);
            #pragma unroll
            for (int ow = 0; ow < 7; ++ow) {
                res[j][ow].x = fmaxf(fmaxf(prev[ow].x, prev[ow + 1].x),
                                     fmaxf(cur[ow].x,  cur[ow + 1].x));
                res[j][ow].y = fmaxf(fmaxf(prev[ow].y, prev[ow + 1].y),
                                     fmaxf(cur[ow].y,  cur[ow + 1].y));
            }
            #pragma unroll
            for (int pw = 0; pw < 8; ++pw) prev[pw] = cur[pw];
        }
    } else {
        float2 prev[8], cur[8];
        sample_row(3, prev);
        #pragma unroll
        for (int j = 0; j < 4; ++j) {
            sample_row(4 + j, cur);
            #pragma unroll
            for (int ow = 0; ow < 7; ++ow) {
                res[j][ow].x = fmaxf(fmaxf(prev[ow].x, prev[ow + 1].x),
                                     fmaxf(cur[ow].x,  cur[ow + 1].x));
                res[j][ow].y = fmaxf(fmaxf(prev[ow].y, prev[ow + 1].y),
                                     fmaxf(cur[ow].y,  cur[ow + 1].y));
            }
            #pragma unroll
            for (int pw = 0; pw < 8; ++pw) prev[pw] = cur[pw];
        }
    }

    // two 128-channel staging phases -> dense float4 stores
    const int group = cp >> 6;          // which 128-channel group I belong to
    const int lc    = (cp & 63) * 2;    // local channel within group
    const int rbase = (half == 0) ? 0 : 3;
    const int nr    = (half == 0) ? 3 : 4;

    #pragma unroll
    for (int g = 0; g < 2; ++g) {
        if (group == g) {
            #pragma unroll
            for (int j = 0; j < 4; ++j) {
                if (j < nr) {
                    #pragma unroll
                    for (int ow = 0; ow < 7; ++ow) {
                        s_out[lc * 49 + (rbase + j) * 7 + ow]       = res[j][ow].x;
                        s_out[(lc + 1) * 49 + (rbase + j) * 7 + ow] = res[j][ow].y;
                    }
                }
            }
        }
        __syncthreads();
        float4* o4 = (float4*)(out + (size_t)r * (FC * 49) + g * (128 * 49));
        const float4* s4 = (const float4*)s_out;
        #pragma unroll
        for (int k = 0; k < 7; ++k) {
            const int idx = k * 256 + tid;
            if (idx < (128 * 49 / 4)) o4[idx] = s4[idx];
        }
        __syncthreads();
    }
}

// ---------------- fallback (NCHW direct) if ws too small ------------------
__global__ __launch_bounds__(256) void roi_align_max_kernel(
    const float* __restrict__ feat, const float* __restrict__ rois,
    float* __restrict__ out, int R)
{
    __shared__ int   s_off[64];
    __shared__ float s_w0[64], s_w1[64], s_w2[64], s_w3[64];
    __shared__ int   s_base;

    const int r   = blockIdx.x;
    const int tid = threadIdx.x;

    if (tid < 64) {
        const float b  = rois[r * 5 + 0];
        const float x1 = rois[r * 5 + 1] * SPATIAL_SCALE;
        const float y1 = rois[r * 5 + 2] * SPATIAL_SCALE;
        const float x2 = rois[r * 5 + 3] * SPATIAL_SCALE;
        const float y2 = rois[r * 5 + 4] * SPATIAL_SCALE;
        const float bin_h = fmaxf(y2 - y1, 0.0f) * (1.0f / 7.0f);
        const float bin_w = fmaxf(x2 - x1, 0.0f) * (1.0f / 7.0f);
        const int ph = tid >> 3;
        const int pw = tid & 7;
        const float h = y1 + (float)ph * bin_h;
        const float w = x1 + (float)pw * bin_w;
        const bool valid = (h >= 0.0f) && (h < (float)FH) &&
                           (w >= 0.0f) && (w < (float)FW);
        const float h0 = fminf(fmaxf(floorf(h), 0.0f), (float)(FH - 2));
        const float w0 = fminf(fmaxf(floorf(w), 0.0f), (float)(FW - 2));
        const float fh = h - h0;
        const float fw = w - w0;
        const float v  = valid ? 1.0f : 0.0f;
        s_off[tid] = (int)h0 * FW + (int)w0;
        s_w0[tid] = (1.0f - fh) * (1.0f - fw) * v;
        s_w1[tid] = (1.0f - fh) * fw * v;
        s_w2[tid] = fh * (1.0f - fw) * v;
        s_w3[tid] = fh * fw * v;
        if (tid == 0) s_base = (int)b * (FC * FHW);
    }
    __syncthreads();

    const int c = tid;
    const float* __restrict__ f = feat + s_base + c * FHW;
    float* __restrict__ outp = out + ((size_t)r * FC + c) * 49;

    float prev[8];
    for (int ph = 0; ph < 8; ++ph) {
        float cur[8];
        #pragma unroll
        for (int pw = 0; pw < 8; ++pw) {
            const int m = ph * 8 + pw;
            const int o = s_off[m];
            cur[pw] = f[o] * s_w0[m] + f[o + 1] * s_w1[m]
                    + f[o + FW] * s_w2[m] + f[o + FW + 1] * s_w3[m];
        }
        if (ph > 0) {
            #pragma unroll
            for (int ow = 0; ow < 7; ++ow)
                outp[(ph - 1) * 7 + ow] =
                    fmaxf(fmaxf(prev[ow], prev[ow + 1]),
                          fmaxf(cur[ow],  cur[ow + 1]));
        }
        #pragma unroll
        for (int pw = 0; pw < 8; ++pw) prev[pw] = cur[pw];
    }
}

extern "C" void kernel_launch(void* const* d_in, const int* in_sizes, int n_in,
                              void* d_out, int out_size, void* d_ws, size_t ws_size,
                              hipStream_t stream) {
    const float* feat = (const float*)d_in[0];
    const float* rois = (const float*)d_in[1];
    float* out = (float*)d_out;
    const int R = in_sizes[1] / 5;
    if (R <= 0) return;

    const size_t needed = (size_t)2 * FC * FHW * sizeof(__half);  // 55.7 MB
    if (ws_size >= needed) {
        __half* featT = (__half*)d_ws;
        transpose_f16_kernel<<<dim3(FHW / 64, FC / 64, 2), 256, 0, stream>>>(feat, featT);
        roi_align_max_f16_kernel<<<R, 256, 0, stream>>>(
            (const __half2*)featT, rois, out, R);
    } else {
        roi_align_max_kernel<<<R, 256, 0, stream>>>(feat, rois, out, R);
    }
}